// Round 17
// baseline (449.830 us; speedup 1.0000x reference)
//
#include <hip/hip_runtime.h>

// SigLIP contrastive loss:
//   logits = emb1 @ emb2^T / 0.07           [B,B], B=8192, D=1024
//   loss = ( sum_i softplus(-l_ii) + sum_{i!=j} softplus(l_ij) ) / B
// R17: occupancy over pipelining. R8-R16 audit: no CU pipe >44% busy ->
// latency-bound at 2 waves/SIMD (LDS dbuf capped residency at 2 blocks/CU).
// Single-buffered 32 KB LDS, 128x128/4-wave blocks -> 5 blocks/CU
// (5 waves/SIMD, __launch_bounds__(256,5), VGPR<=102). Serial per block
// {stage -> sync -> reads -> sync -> stage T+1 -> MFMA}; 5 independent
// blocks fill the pipes. Expected new cap: LDS pipe ~768 cyc/K-tile/CU.

#define B_DIM 8192
#define K_DIM 1024
#define BT 128                 // tile rows == cols
#define BKB 128                // K bytes per K-tile
#define NT (K_DIM / BKB)       // 8 K-tiles
#define BRICK 16384            // one (128-row panel, K-tile) brick
#define PANEL_BYTES (NT * BRICK)

typedef int i32x4 __attribute__((ext_vector_type(4)));
typedef int i32x8 __attribute__((ext_vector_type(8)));
typedef float f32x4 __attribute__((ext_vector_type(4)));

// f32 -> fp8 e4m3 brick permutation (PANEL=128). One thread = 16 out bytes.
// Brick offset = fb*2048 + h*1024 + kch*256 + lr*16.
// Source: row = p*128 + fb*16 + lr, k byte = t*128 + kch*32 + h*16.
__device__ __forceinline__ void brick_store(const float* __restrict__ in,
                                            unsigned char* __restrict__ out,
                                            float scale, int i) {
  const int o = i * 16;
  const int b = o >> 14;                  // brick index
  const int p = b >> 3, t = b & 7;        // panel, K-tile
  const int w = o & (BRICK - 1);
  const int fb = w >> 11;
  const int h = (w >> 10) & 1;
  const int kch = (w >> 8) & 3;
  const int lr = (w >> 4) & 15;
  const int row = p * 128 + fb * 16 + lr;
  const int kb = t * 128 + kch * 32 + h * 16;
  const float4* src = (const float4*)(in + (size_t)row * K_DIM + kb);
  float4 v0 = src[0], v1 = src[1], v2 = src[2], v3 = src[3];
  unsigned w0 = 0, w1 = 0, w2 = 0, w3 = 0;
  w0 = __builtin_amdgcn_cvt_pk_fp8_f32(v0.x * scale, v0.y * scale, w0, 0);
  w0 = __builtin_amdgcn_cvt_pk_fp8_f32(v0.z * scale, v0.w * scale, w0, 1);
  w1 = __builtin_amdgcn_cvt_pk_fp8_f32(v1.x * scale, v1.y * scale, w1, 0);
  w1 = __builtin_amdgcn_cvt_pk_fp8_f32(v1.z * scale, v1.w * scale, w1, 1);
  w2 = __builtin_amdgcn_cvt_pk_fp8_f32(v2.x * scale, v2.y * scale, w2, 0);
  w2 = __builtin_amdgcn_cvt_pk_fp8_f32(v2.z * scale, v2.w * scale, w2, 1);
  w3 = __builtin_amdgcn_cvt_pk_fp8_f32(v3.x * scale, v3.y * scale, w3, 0);
  w3 = __builtin_amdgcn_cvt_pk_fp8_f32(v3.z * scale, v3.w * scale, w3, 1);
  *(uint4*)(out + o) = make_uint4(w0, w1, w2, w3);
}

__global__ __launch_bounds__(256) void cvt_fused(
    const float* __restrict__ e1, const float* __restrict__ e2,
    unsigned char* __restrict__ A8, unsigned char* __restrict__ B8,
    int nbA, float scaleA) {
  const int blk = blockIdx.x;
  if (blk < nbA)
    brick_store(e1, A8, scaleA, blk * 256 + threadIdx.x);
  else
    brick_store(e2, B8, 1.0f, (blk - nbA) * 256 + threadIdx.x);
}

// Cheap softplus accumulate: softplus(x) = max(x,0) + log(1+exp(-|x|)).
template <bool DIAG>
__device__ __forceinline__ float softplus_sum(const f32x4 (&acc)[4][4],
                                              int rbase, int cbase) {
  float lin = 0.f, cor = 0.f;
#pragma unroll
  for (int m = 0; m < 4; ++m) {
#pragma unroll
    for (int n = 0; n < 4; ++n) {
#pragma unroll
      for (int r = 0; r < 4; ++r) {
        float x = acc[m][n][r];
        if (DIAG) {
          int row = rbase + m * 16 + r;
          int col = cbase + n * 16;
          if (row == col) x = -x;  // diagonal: softplus(-l_ii)
        }
        lin += fmaxf(x, 0.f);
        cor += __logf(1.f + __expf(-fabsf(x)));
      }
    }
  }
  return lin + cor;
}

// Staging: 32 KB/K-tile as 32 linear 1024B slices (A 16, B 16); wave w takes
// slices w*4..w*4+3 of each operand. srcA/srcB include wave*4096 + lane*16.
#define STAGEA(Q, TI)                                                         \
  __builtin_amdgcn_global_load_lds(                                           \
      (const __attribute__((address_space(1))) void*)(const void*)(           \
          srcA + (TI) * BRICK + (Q) * 1024),                                  \
      (__attribute__((address_space(3))) void*)(void*)(                       \
          lds + dA + (Q) * 1024),                                             \
      16, 0, 0)
#define STAGEB(Q, TI)                                                         \
  __builtin_amdgcn_global_load_lds(                                           \
      (const __attribute__((address_space(1))) void*)(const void*)(           \
          srcB + (TI) * BRICK + (Q) * 1024),                                  \
      (__attribute__((address_space(3))) void*)(void*)(                       \
          lds + dB + (Q) * 1024),                                             \
      16, 0, 0)
#define STAGE8(TI)                                                            \
  STAGEA(0, TI); STAGEA(1, TI); STAGEA(2, TI); STAGEA(3, TI);                 \
  STAGEB(0, TI); STAGEB(1, TI); STAGEB(2, TI); STAGEB(3, TI)

// Fragment read: two conflict-free ds_read_b128 (lane*16 stride) + combine.
#define LDA(OUT, M)                                                           \
  {                                                                           \
    const unsigned char* _b = ldsL + ((wr * 4 + (M)) << 11);                  \
    i32x4 _lo = *(const i32x4*)(_b);                                          \
    i32x4 _hi = *(const i32x4*)(_b + 1024);                                   \
    OUT = __builtin_shufflevector(_lo, _hi, 0, 1, 2, 3, 4, 5, 6, 7);          \
  }
#define LDB(OUT, N)                                                           \
  {                                                                           \
    const unsigned char* _b = ldsL + (16384 + ((wc * 4 + (N)) << 11));        \
    i32x4 _lo = *(const i32x4*)(_b);                                          \
    i32x4 _hi = *(const i32x4*)(_b + 1024);                                   \
    OUT = __builtin_shufflevector(_lo, _hi, 0, 1, 2, 3, 4, 5, 6, 7);          \
  }

#define MFMA(AF, BF, M, N)                                                    \
  acc[M][N] = __builtin_amdgcn_mfma_scale_f32_16x16x128_f8f6f4(               \
      AF, BF, acc[M][N], 0, 0, 0, 127, 0, 127)

__global__ __launch_bounds__(256, 5) void siglip_gemm(
    const unsigned char* __restrict__ A8,
    const unsigned char* __restrict__ B8,
    float* __restrict__ partials) {
  __shared__ unsigned char lds[32768];  // single buffer: A 16K + B 16K

  const int tid = threadIdx.x;
  const int wave = tid >> 6;
  const int lane = tid & 63;
  const int wr = wave >> 1;  // 0..1 -> 64-row strip
  const int wc = wave & 1;   // 0..1 -> 64-col strip
  const int brow = blockIdx.y;
  const int bcol = blockIdx.x;

  f32x4 acc[4][4];
#pragma unroll
  for (int m = 0; m < 4; ++m)
#pragma unroll
    for (int n = 0; n < 4; ++n) acc[m][n] = f32x4{0.f, 0.f, 0.f, 0.f};

  const unsigned char* srcA =
      A8 + (size_t)brow * PANEL_BYTES + wave * 4096 + (lane << 4);
  const unsigned char* srcB =
      B8 + (size_t)bcol * PANEL_BYTES + wave * 4096 + (lane << 4);
  const int dA = wave * 4096;
  const int dB = 16384 + wave * 4096;
  const unsigned char* ldsL = lds + (lane << 4);  // per-lane read base

  // Prologue: stage tile 0.
  STAGE8(0);

#pragma unroll
  for (int T = 0; T < NT; ++T) {
    // syncthreads drains vmcnt (stage T landed for ALL waves) + lgkm.
    __syncthreads();

    // Fragment reads for tile T (16x ds_read_b128, conflict-free).
    i32x8 a0, a1, a2, a3, b0, b1, b2, b3;
    LDA(a0, 0); LDB(b0, 0); LDB(b1, 1); LDB(b2, 2); LDB(b3, 3);
    LDA(a1, 1); LDA(a2, 2); LDA(a3, 3);

    // syncthreads drains lgkm (everyone's reads in registers) -> buffer free.
    __syncthreads();

    // Stage tile T+1 into the (single) buffer; its L2 latency hides under
    // the MFMA cluster below. sched_barrier keeps the issue ahead of MFMAs.
    if (T < NT - 1) {
      STAGE8(T + 1);
      __builtin_amdgcn_sched_barrier(0);
    }

    __builtin_amdgcn_s_setprio(1);
    MFMA(a0, b0, 0, 0); MFMA(a0, b1, 0, 1); MFMA(a0, b2, 0, 2); MFMA(a0, b3, 0, 3);
    MFMA(a1, b0, 1, 0); MFMA(a1, b1, 1, 1); MFMA(a1, b2, 1, 2); MFMA(a1, b3, 1, 3);
    MFMA(a2, b0, 2, 0); MFMA(a2, b1, 2, 1); MFMA(a2, b2, 2, 2); MFMA(a2, b3, 2, 3);
    MFMA(a3, b0, 3, 0); MFMA(a3, b1, 3, 1); MFMA(a3, b2, 3, 2); MFMA(a3, b3, 3, 3);
    __builtin_amdgcn_s_setprio(0);
  }

  // Epilogue. C/D 16x16 map: col = lane&15, row = (lane>>4)*4 + r.
  const int rbase = brow * BT + wr * 64 + (lane >> 4) * 4;
  const int cbase = bcol * BT + wc * 64 + (lane & 15);
  float lsum;
  if (brow == bcol)
    lsum = softplus_sum<true>(acc, rbase, cbase);
  else
    lsum = softplus_sum<false>(acc, rbase, cbase);

#pragma unroll
  for (int off = 32; off > 0; off >>= 1) lsum += __shfl_down(lsum, off);

  // Reuse the (dead) staging buffer for the cross-wave reduction to keep
  // block LDS at exactly 32768 B (5 blocks/CU).
  float* wsum = (float*)lds;
  __syncthreads();
  if (lane == 0) wsum[wave] = lsum;
  __syncthreads();
  if (tid == 0)
    partials[blockIdx.y * gridDim.x + blockIdx.x] =
        wsum[0] + wsum[1] + wsum[2] + wsum[3];
}

__global__ void reduce_kernel(const float* __restrict__ partials, int n,
                              float* __restrict__ out) {
  __shared__ float s[256];
  float v = 0.f;
  for (int i = threadIdx.x; i < n; i += 256) v += partials[i];
  s[threadIdx.x] = v;
  __syncthreads();
  for (int off = 128; off > 0; off >>= 1) {
    if ((int)threadIdx.x < off) s[threadIdx.x] += s[threadIdx.x + off];
    __syncthreads();
  }
  if (threadIdx.x == 0) out[0] = s[0] / (float)B_DIM;
}

extern "C" void kernel_launch(void* const* d_in, const int* in_sizes, int n_in,
                              void* d_out, int out_size, void* d_ws, size_t ws_size,
                              hipStream_t stream) {
  const float* emb1 = (const float*)d_in[0];
  const float* emb2 = (const float*)d_in[1];

  unsigned char* A8 = (unsigned char*)d_ws;                // 8 MB (bricked)
  unsigned char* B8 = A8 + (size_t)B_DIM * K_DIM;          // 8 MB (bricked)
  float* partials = (float*)(B8 + (size_t)B_DIM * K_DIM);  // 16 KB

  const float INV_T = 1.0f / 0.07f;
  const int nbA = (B_DIM * K_DIM / 16) / 256;  // 2048 blocks per operand
  cvt_fused<<<2 * nbA, 256, 0, stream>>>(emb1, emb2, A8, B8, nbA, INV_T);

  dim3 grid(B_DIM / BT, B_DIM / BT);  // 64 x 64
  siglip_gemm<<<grid, 256, 0, stream>>>(A8, B8, partials);

  const int nparts = (B_DIM / BT) * (B_DIM / BT);
  reduce_kernel<<<1, 256, 0, stream>>>(partials, nparts, (float*)d_out);
}

// Round 18
// 110.329 us; speedup vs baseline: 4.0772x; 4.0772x over previous
//
#include <hip/hip_runtime.h>

// SigLIP contrastive loss:
//   logits = emb1 @ emb2^T / 0.07           [B,B], B=8192, D=1024
//   loss = ( sum_i softplus(-l_ii) + sum_{i!=j} softplus(l_ij) ) / B
// R18: occupancy without spill. R17's single-buffer forced 143 live regs at
// the drain barrier (cap 102 -> spill). Mixed buffering: A dbuf 32 KB +
// B single 16 KB = 48 KB/block -> 3 blocks/CU (3 waves/SIMD, +50%),
// __launch_bounds__(256,3) cap 170 >> pressure ~111 (only B frags + acc
// live at the forced drain; A reads issue after the barrier and interleave
// into MFMAs). Raw s_barrier + lgkmcnt(0) only (no mid-loop vmcnt drain).

#define B_DIM 8192
#define K_DIM 1024
#define BT 128                 // tile rows == cols
#define BKB 128                // K bytes per K-tile
#define NT (K_DIM / BKB)       // 8 K-tiles
#define BRICK 16384            // one (128-row panel, K-tile) brick
#define PANEL_BYTES (NT * BRICK)

typedef int i32x4 __attribute__((ext_vector_type(4)));
typedef int i32x8 __attribute__((ext_vector_type(8)));
typedef float f32x4 __attribute__((ext_vector_type(4)));

// f32 -> fp8 e4m3 brick permutation (PANEL=128). One thread = 16 out bytes.
// Brick offset = fb*2048 + h*1024 + kch*256 + lr*16.
// Source: row = p*128 + fb*16 + lr, k byte = t*128 + kch*32 + h*16.
__device__ __forceinline__ void brick_store(const float* __restrict__ in,
                                            unsigned char* __restrict__ out,
                                            float scale, int i) {
  const int o = i * 16;
  const int b = o >> 14;                  // brick index
  const int p = b >> 3, t = b & 7;        // panel, K-tile
  const int w = o & (BRICK - 1);
  const int fb = w >> 11;
  const int h = (w >> 10) & 1;
  const int kch = (w >> 8) & 3;
  const int lr = (w >> 4) & 15;
  const int row = p * 128 + fb * 16 + lr;
  const int kb = t * 128 + kch * 32 + h * 16;
  const float4* src = (const float4*)(in + (size_t)row * K_DIM + kb);
  float4 v0 = src[0], v1 = src[1], v2 = src[2], v3 = src[3];
  unsigned w0 = 0, w1 = 0, w2 = 0, w3 = 0;
  w0 = __builtin_amdgcn_cvt_pk_fp8_f32(v0.x * scale, v0.y * scale, w0, 0);
  w0 = __builtin_amdgcn_cvt_pk_fp8_f32(v0.z * scale, v0.w * scale, w0, 1);
  w1 = __builtin_amdgcn_cvt_pk_fp8_f32(v1.x * scale, v1.y * scale, w1, 0);
  w1 = __builtin_amdgcn_cvt_pk_fp8_f32(v1.z * scale, v1.w * scale, w1, 1);
  w2 = __builtin_amdgcn_cvt_pk_fp8_f32(v2.x * scale, v2.y * scale, w2, 0);
  w2 = __builtin_amdgcn_cvt_pk_fp8_f32(v2.z * scale, v2.w * scale, w2, 1);
  w3 = __builtin_amdgcn_cvt_pk_fp8_f32(v3.x * scale, v3.y * scale, w3, 0);
  w3 = __builtin_amdgcn_cvt_pk_fp8_f32(v3.z * scale, v3.w * scale, w3, 1);
  *(uint4*)(out + o) = make_uint4(w0, w1, w2, w3);
}

__global__ __launch_bounds__(256) void cvt_fused(
    const float* __restrict__ e1, const float* __restrict__ e2,
    unsigned char* __restrict__ A8, unsigned char* __restrict__ B8,
    int nbA, float scaleA) {
  const int blk = blockIdx.x;
  if (blk < nbA)
    brick_store(e1, A8, scaleA, blk * 256 + threadIdx.x);
  else
    brick_store(e2, B8, 1.0f, (blk - nbA) * 256 + threadIdx.x);
}

// Cheap softplus accumulate: softplus(x) = max(x,0) + log(1+exp(-|x|)).
template <bool DIAG>
__device__ __forceinline__ float softplus_sum(const f32x4 (&acc)[4][4],
                                              int rbase, int cbase) {
  float lin = 0.f, cor = 0.f;
#pragma unroll
  for (int m = 0; m < 4; ++m) {
#pragma unroll
    for (int n = 0; n < 4; ++n) {
#pragma unroll
      for (int r = 0; r < 4; ++r) {
        float x = acc[m][n][r];
        if (DIAG) {
          int row = rbase + m * 16 + r;
          int col = cbase + n * 16;
          if (row == col) x = -x;  // diagonal: softplus(-l_ii)
        }
        lin += fmaxf(x, 0.f);
        cor += __logf(1.f + __expf(-fabsf(x)));
      }
    }
  }
  return lin + cor;
}

// Staging: wave w takes 4 slices (1 KB each) of A and of B per K-tile.
// LDS map: A dbuf [0,16K)+[16K,32K), B single [32K,48K).
#define STAGEA(SB, Q, TI)                                                     \
  __builtin_amdgcn_global_load_lds(                                           \
      (const __attribute__((address_space(1))) void*)(const void*)(           \
          srcA + (TI) * BRICK + (Q) * 1024),                                  \
      (__attribute__((address_space(3))) void*)(void*)(                       \
          lds + (SB) + dAW + (Q) * 1024),                                     \
      16, 0, 0)
#define STAGEB(Q, TI)                                                         \
  __builtin_amdgcn_global_load_lds(                                           \
      (const __attribute__((address_space(1))) void*)(const void*)(           \
          srcB + (TI) * BRICK + (Q) * 1024),                                  \
      (__attribute__((address_space(3))) void*)(void*)(                       \
          lds + 32768 + dAW + (Q) * 1024),                                    \
      16, 0, 0)
#define STG4A(SB, TI) \
  STAGEA(SB, 0, TI); STAGEA(SB, 1, TI); STAGEA(SB, 2, TI); STAGEA(SB, 3, TI)
#define STG4B(TI) \
  STAGEB(0, TI); STAGEB(1, TI); STAGEB(2, TI); STAGEB(3, TI)

// Fragment read: two conflict-free ds_read_b128 (lane*16 stride) + combine.
#define LDA(OUT, AB, M)                                                       \
  {                                                                           \
    const unsigned char* _b = ldsL + ((AB) + ((wr * 4 + (M)) << 11));         \
    i32x4 _lo = *(const i32x4*)(_b);                                          \
    i32x4 _hi = *(const i32x4*)(_b + 1024);                                   \
    OUT = __builtin_shufflevector(_lo, _hi, 0, 1, 2, 3, 4, 5, 6, 7);          \
  }
#define LDB(OUT, N)                                                           \
  {                                                                           \
    const unsigned char* _b = ldsL + (32768 + ((wc * 4 + (N)) << 11));        \
    i32x4 _lo = *(const i32x4*)(_b);                                          \
    i32x4 _hi = *(const i32x4*)(_b + 1024);                                   \
    OUT = __builtin_shufflevector(_lo, _hi, 0, 1, 2, 3, 4, 5, 6, 7);          \
  }

#define MFMA(AF, BF, M, N)                                                    \
  acc[M][N] = __builtin_amdgcn_mfma_scale_f32_16x16x128_f8f6f4(               \
      AF, BF, acc[M][N], 0, 0, 0, 127, 0, 127)

__global__ __launch_bounds__(256, 3) void siglip_gemm(
    const unsigned char* __restrict__ A8,
    const unsigned char* __restrict__ B8,
    float* __restrict__ partials) {
  __shared__ unsigned char lds[49152];  // A dbuf 32K | B single 16K

  const int tid = threadIdx.x;
  const int wave = tid >> 6;
  const int lane = tid & 63;
  const int wr = wave >> 1;  // 0..1 -> 64-row strip
  const int wc = wave & 1;   // 0..1 -> 64-col strip
  const int brow = blockIdx.y;
  const int bcol = blockIdx.x;

  f32x4 acc[4][4];
#pragma unroll
  for (int m = 0; m < 4; ++m)
#pragma unroll
    for (int n = 0; n < 4; ++n) acc[m][n] = f32x4{0.f, 0.f, 0.f, 0.f};

  const unsigned char* srcA =
      A8 + (size_t)brow * PANEL_BYTES + wave * 4096 + (lane << 4);
  const unsigned char* srcB =
      B8 + (size_t)bcol * PANEL_BYTES + wave * 4096 + (lane << 4);
  const int dAW = wave * 4096;                   // wave's staging sub-region
  const unsigned char* ldsL = lds + (lane << 4); // per-lane read base

  // Prologue: stage tile 0 (A -> abuf0, B -> bbuf), drain, publish.
  STG4A(0, 0); STG4B(0);
  asm volatile("s_waitcnt vmcnt(0)" ::: "memory");
  __builtin_amdgcn_s_barrier();
  __builtin_amdgcn_sched_barrier(0);

#pragma unroll
  for (int T = 0; T < NT; ++T) {
    const int ab = (T & 1) * 16384;   // A read buffer
    const int sab = ab ^ 16384;       // A stage buffer (holds consumed T-1)

    // B fragment reads for tile T (single-buffered: must drain before the
    // B overwrite below). A staging issues now -> latency hides under the
    // barrier + MFMA cluster.
    i32x8 b0, b1, b2, b3;
    LDB(b0, 0); LDB(b1, 1); LDB(b2, 2); LDB(b3, 3);
    if (T < NT - 1) { STG4A(sab, T + 1); }

    // Own B reads in regs, then join: all waves' B(T) reads are complete.
    asm volatile("s_waitcnt lgkmcnt(0)" ::: "memory");
    __builtin_amdgcn_s_barrier();
    __builtin_amdgcn_sched_barrier(0);

    // B(T+1) overwrite now safe. A reads (dbuf, no hazard) issue here and
    // interleave into the MFMA cluster via compiler counted lgkmcnt.
    if (T < NT - 1) { STG4B(T + 1); }
    i32x8 a0, a1, a2, a3;
    LDA(a0, ab, 0); LDA(a1, ab, 1); LDA(a2, ab, 2); LDA(a3, ab, 3);

    __builtin_amdgcn_s_setprio(1);
    MFMA(a0, b0, 0, 0); MFMA(a0, b1, 0, 1); MFMA(a0, b2, 0, 2); MFMA(a0, b3, 0, 3);
    MFMA(a1, b0, 1, 0); MFMA(a1, b1, 1, 1); MFMA(a1, b2, 1, 2); MFMA(a1, b3, 1, 3);
    MFMA(a2, b0, 2, 0); MFMA(a2, b1, 2, 1); MFMA(a2, b2, 2, 2); MFMA(a2, b3, 2, 3);
    MFMA(a3, b0, 3, 0); MFMA(a3, b1, 3, 1); MFMA(a3, b2, 3, 2); MFMA(a3, b3, 3, 3);
    __builtin_amdgcn_s_setprio(0);

    if (T < NT - 1) {
      // Own staging of T+1 (A and B) landed; barrier publishes cross-wave.
      // A(T) reads are complete here (MFMAs consumed them) -> next iter may
      // overwrite abuf^1 safely after this barrier.
      asm volatile("s_waitcnt vmcnt(0)" ::: "memory");
      __builtin_amdgcn_s_barrier();
      __builtin_amdgcn_sched_barrier(0);
    }
  }

  // Epilogue. C/D 16x16 map: col = lane&15, row = (lane>>4)*4 + r.
  const int rbase = brow * BT + wr * 64 + (lane >> 4) * 4;
  const int cbase = bcol * BT + wc * 64 + (lane & 15);
  float lsum;
  if (brow == bcol)
    lsum = softplus_sum<true>(acc, rbase, cbase);
  else
    lsum = softplus_sum<false>(acc, rbase, cbase);

#pragma unroll
  for (int off = 32; off > 0; off >>= 1) lsum += __shfl_down(lsum, off);

  // Reuse the (dead) B buffer for cross-wave reduction (keeps LDS at 48 KB).
  float* wsum = (float*)(lds + 32768);
  __syncthreads();
  if (lane == 0) wsum[wave] = lsum;
  __syncthreads();
  if (tid == 0)
    partials[blockIdx.y * gridDim.x + blockIdx.x] =
        wsum[0] + wsum[1] + wsum[2] + wsum[3];
}

__global__ void reduce_kernel(const float* __restrict__ partials, int n,
                              float* __restrict__ out) {
  __shared__ float s[256];
  float v = 0.f;
  for (int i = threadIdx.x; i < n; i += 256) v += partials[i];
  s[threadIdx.x] = v;
  __syncthreads();
  for (int off = 128; off > 0; off >>= 1) {
    if ((int)threadIdx.x < off) s[threadIdx.x] += s[threadIdx.x + off];
    __syncthreads();
  }
  if (threadIdx.x == 0) out[0] = s[0] / (float)B_DIM;
}

extern "C" void kernel_launch(void* const* d_in, const int* in_sizes, int n_in,
                              void* d_out, int out_size, void* d_ws, size_t ws_size,
                              hipStream_t stream) {
  const float* emb1 = (const float*)d_in[0];
  const float* emb2 = (const float*)d_in[1];

  unsigned char* A8 = (unsigned char*)d_ws;                // 8 MB (bricked)
  unsigned char* B8 = A8 + (size_t)B_DIM * K_DIM;          // 8 MB (bricked)
  float* partials = (float*)(B8 + (size_t)B_DIM * K_DIM);  // 16 KB

  const float INV_T = 1.0f / 0.07f;
  const int nbA = (B_DIM * K_DIM / 16) / 256;  // 2048 blocks per operand
  cvt_fused<<<2 * nbA, 256, 0, stream>>>(emb1, emb2, A8, B8, nbA, INV_T);

  dim3 grid(B_DIM / BT, B_DIM / BT);  // 64 x 64
  siglip_gemm<<<grid, 256, 0, stream>>>(A8, B8, partials);

  const int nparts = (B_DIM / BT) * (B_DIM / BT);
  reduce_kernel<<<1, 256, 0, stream>>>(partials, nparts, (float*)d_out);
}

// Round 19
// 109.522 us; speedup vs baseline: 4.1072x; 1.0074x over previous
//
#include <hip/hip_runtime.h>

// SigLIP contrastive loss:
//   logits = emb1 @ emb2^T / 0.07           [B,B], B=8192, D=1024
//   loss = ( sum_i softplus(-l_ii) + sum_{i!=j} softplus(l_ij) ) / B
// R19: R18 (A dbuf 32K + B single 16K, 3 blocks/CU, 3 waves/SIMD) with
// staging-drain latency surgery: stage B(T+1) BEFORE A(T+1); end-of-iter
// drain relaxed to vmcnt(4) (waits B only, A stays in flight across the
// barrier); A(T+1) drained at next iter's mid-barrier (vmcnt(0) before the
// barrier that precedes A-reads). A's cover grows ~900 -> ~1500 cyc and the
// end drain no longer exposes A's L2 tail. Otherwise byte-identical to R18.

#define B_DIM 8192
#define K_DIM 1024
#define BT 128                 // tile rows == cols
#define BKB 128                // K bytes per K-tile
#define NT (K_DIM / BKB)       // 8 K-tiles
#define BRICK 16384            // one (128-row panel, K-tile) brick
#define PANEL_BYTES (NT * BRICK)

typedef int i32x4 __attribute__((ext_vector_type(4)));
typedef int i32x8 __attribute__((ext_vector_type(8)));
typedef float f32x4 __attribute__((ext_vector_type(4)));

// f32 -> fp8 e4m3 brick permutation (PANEL=128). One thread = 16 out bytes.
// Brick offset = fb*2048 + h*1024 + kch*256 + lr*16.
// Source: row = p*128 + fb*16 + lr, k byte = t*128 + kch*32 + h*16.
__device__ __forceinline__ void brick_store(const float* __restrict__ in,
                                            unsigned char* __restrict__ out,
                                            float scale, int i) {
  const int o = i * 16;
  const int b = o >> 14;                  // brick index
  const int p = b >> 3, t = b & 7;        // panel, K-tile
  const int w = o & (BRICK - 1);
  const int fb = w >> 11;
  const int h = (w >> 10) & 1;
  const int kch = (w >> 8) & 3;
  const int lr = (w >> 4) & 15;
  const int row = p * 128 + fb * 16 + lr;
  const int kb = t * 128 + kch * 32 + h * 16;
  const float4* src = (const float4*)(in + (size_t)row * K_DIM + kb);
  float4 v0 = src[0], v1 = src[1], v2 = src[2], v3 = src[3];
  unsigned w0 = 0, w1 = 0, w2 = 0, w3 = 0;
  w0 = __builtin_amdgcn_cvt_pk_fp8_f32(v0.x * scale, v0.y * scale, w0, 0);
  w0 = __builtin_amdgcn_cvt_pk_fp8_f32(v0.z * scale, v0.w * scale, w0, 1);
  w1 = __builtin_amdgcn_cvt_pk_fp8_f32(v1.x * scale, v1.y * scale, w1, 0);
  w1 = __builtin_amdgcn_cvt_pk_fp8_f32(v1.z * scale, v1.w * scale, w1, 1);
  w2 = __builtin_amdgcn_cvt_pk_fp8_f32(v2.x * scale, v2.y * scale, w2, 0);
  w2 = __builtin_amdgcn_cvt_pk_fp8_f32(v2.z * scale, v2.w * scale, w2, 1);
  w3 = __builtin_amdgcn_cvt_pk_fp8_f32(v3.x * scale, v3.y * scale, w3, 0);
  w3 = __builtin_amdgcn_cvt_pk_fp8_f32(v3.z * scale, v3.w * scale, w3, 1);
  *(uint4*)(out + o) = make_uint4(w0, w1, w2, w3);
}

__global__ __launch_bounds__(256) void cvt_fused(
    const float* __restrict__ e1, const float* __restrict__ e2,
    unsigned char* __restrict__ A8, unsigned char* __restrict__ B8,
    int nbA, float scaleA) {
  const int blk = blockIdx.x;
  if (blk < nbA)
    brick_store(e1, A8, scaleA, blk * 256 + threadIdx.x);
  else
    brick_store(e2, B8, 1.0f, (blk - nbA) * 256 + threadIdx.x);
}

// Cheap softplus accumulate: softplus(x) = max(x,0) + log(1+exp(-|x|)).
template <bool DIAG>
__device__ __forceinline__ float softplus_sum(const f32x4 (&acc)[4][4],
                                              int rbase, int cbase) {
  float lin = 0.f, cor = 0.f;
#pragma unroll
  for (int m = 0; m < 4; ++m) {
#pragma unroll
    for (int n = 0; n < 4; ++n) {
#pragma unroll
      for (int r = 0; r < 4; ++r) {
        float x = acc[m][n][r];
        if (DIAG) {
          int row = rbase + m * 16 + r;
          int col = cbase + n * 16;
          if (row == col) x = -x;  // diagonal: softplus(-l_ii)
        }
        lin += fmaxf(x, 0.f);
        cor += __logf(1.f + __expf(-fabsf(x)));
      }
    }
  }
  return lin + cor;
}

// Staging: wave w takes 4 slices (1 KB each) of A and of B per K-tile.
// LDS map: A dbuf [0,16K)+[16K,32K), B single [32K,48K).
#define STAGEA(SB, Q, TI)                                                     \
  __builtin_amdgcn_global_load_lds(                                           \
      (const __attribute__((address_space(1))) void*)(const void*)(           \
          srcA + (TI) * BRICK + (Q) * 1024),                                  \
      (__attribute__((address_space(3))) void*)(void*)(                       \
          lds + (SB) + dAW + (Q) * 1024),                                     \
      16, 0, 0)
#define STAGEB(Q, TI)                                                         \
  __builtin_amdgcn_global_load_lds(                                           \
      (const __attribute__((address_space(1))) void*)(const void*)(           \
          srcB + (TI) * BRICK + (Q) * 1024),                                  \
      (__attribute__((address_space(3))) void*)(void*)(                       \
          lds + 32768 + dAW + (Q) * 1024),                                    \
      16, 0, 0)
#define STG4A(SB, TI) \
  STAGEA(SB, 0, TI); STAGEA(SB, 1, TI); STAGEA(SB, 2, TI); STAGEA(SB, 3, TI)
#define STG4B(TI) \
  STAGEB(0, TI); STAGEB(1, TI); STAGEB(2, TI); STAGEB(3, TI)

// Fragment read: two conflict-free ds_read_b128 (lane*16 stride) + combine.
#define LDA(OUT, AB, M)                                                       \
  {                                                                           \
    const unsigned char* _b = ldsL + ((AB) + ((wr * 4 + (M)) << 11));         \
    i32x4 _lo = *(const i32x4*)(_b);                                          \
    i32x4 _hi = *(const i32x4*)(_b + 1024);                                   \
    OUT = __builtin_shufflevector(_lo, _hi, 0, 1, 2, 3, 4, 5, 6, 7);          \
  }
#define LDB(OUT, N)                                                           \
  {                                                                           \
    const unsigned char* _b = ldsL + (32768 + ((wc * 4 + (N)) << 11));        \
    i32x4 _lo = *(const i32x4*)(_b);                                          \
    i32x4 _hi = *(const i32x4*)(_b + 1024);                                   \
    OUT = __builtin_shufflevector(_lo, _hi, 0, 1, 2, 3, 4, 5, 6, 7);          \
  }

#define MFMA(AF, BF, M, N)                                                    \
  acc[M][N] = __builtin_amdgcn_mfma_scale_f32_16x16x128_f8f6f4(               \
      AF, BF, acc[M][N], 0, 0, 0, 127, 0, 127)

__global__ __launch_bounds__(256, 3) void siglip_gemm(
    const unsigned char* __restrict__ A8,
    const unsigned char* __restrict__ B8,
    float* __restrict__ partials) {
  __shared__ unsigned char lds[49152];  // A dbuf 32K | B single 16K

  const int tid = threadIdx.x;
  const int wave = tid >> 6;
  const int lane = tid & 63;
  const int wr = wave >> 1;  // 0..1 -> 64-row strip
  const int wc = wave & 1;   // 0..1 -> 64-col strip
  const int brow = blockIdx.y;
  const int bcol = blockIdx.x;

  f32x4 acc[4][4];
#pragma unroll
  for (int m = 0; m < 4; ++m)
#pragma unroll
    for (int n = 0; n < 4; ++n) acc[m][n] = f32x4{0.f, 0.f, 0.f, 0.f};

  const unsigned char* srcA =
      A8 + (size_t)brow * PANEL_BYTES + wave * 4096 + (lane << 4);
  const unsigned char* srcB =
      B8 + (size_t)bcol * PANEL_BYTES + wave * 4096 + (lane << 4);
  const int dAW = wave * 4096;                   // wave's staging sub-region
  const unsigned char* ldsL = lds + (lane << 4); // per-lane read base

  // Prologue: stage tile 0 (A -> abuf0, B -> bbuf), drain, publish.
  STG4A(0, 0); STG4B(0);
  asm volatile("s_waitcnt vmcnt(0)" ::: "memory");
  __builtin_amdgcn_s_barrier();
  __builtin_amdgcn_sched_barrier(0);

#pragma unroll
  for (int T = 0; T < NT; ++T) {
    const int ab = (T & 1) * 16384;   // A read buffer (tile T)
    const int sab = ab ^ 16384;       // A stage buffer (holds consumed T-1)

    // B fragment reads for tile T (single-buffered; staged + barrier'd by
    // the end of iter T-1).
    i32x8 b0, b1, b2, b3;
    LDB(b0, 0); LDB(b1, 1); LDB(b2, 2); LDB(b3, 3);

    // Own B reads in regs (lgkm) AND A(T) staging drained (vmcnt 0 — A was
    // left in flight across the end barrier of iter T-1 for extra cover).
    // Barrier then publishes A(T) cross-wave and certifies B buffer free.
    asm volatile("s_waitcnt lgkmcnt(0)" ::: "memory");
    asm volatile("s_waitcnt vmcnt(0)" ::: "memory");
    __builtin_amdgcn_s_barrier();
    __builtin_amdgcn_sched_barrier(0);

    // Stage B(T+1) first (drained at end-of-iter), then A(T+1) (drained at
    // next iter's mid-barrier -> ~1500 cyc cover).
    if (T < NT - 1) { STG4B(T + 1); STG4A(sab, T + 1); }

    // A reads (tile T; drained above) interleave into the MFMA cluster via
    // compiler counted lgkmcnt.
    i32x8 a0, a1, a2, a3;
    LDA(a0, ab, 0); LDA(a1, ab, 1); LDA(a2, ab, 2); LDA(a3, ab, 3);

    __builtin_amdgcn_s_setprio(1);
    MFMA(a0, b0, 0, 0); MFMA(a0, b1, 0, 1); MFMA(a0, b2, 0, 2); MFMA(a0, b3, 0, 3);
    MFMA(a1, b0, 1, 0); MFMA(a1, b1, 1, 1); MFMA(a1, b2, 1, 2); MFMA(a1, b3, 1, 3);
    MFMA(a2, b0, 2, 0); MFMA(a2, b1, 2, 1); MFMA(a2, b2, 2, 2); MFMA(a2, b3, 2, 3);
    MFMA(a3, b0, 3, 0); MFMA(a3, b1, 3, 1); MFMA(a3, b2, 3, 2); MFMA(a3, b3, 3, 3);
    __builtin_amdgcn_s_setprio(0);

    if (T < NT - 1) {
      // Wait only B(T+1) (the 4 OLDEST of the 8 in flight): vmcnt(4).
      // A(T+1)'s 4 loads may stay in flight across the barrier; they are
      // drained at the next iteration's mid-barrier before any A read.
      asm volatile("s_waitcnt vmcnt(4)" ::: "memory");
      __builtin_amdgcn_s_barrier();
      __builtin_amdgcn_sched_barrier(0);
    }
  }

  // Epilogue. C/D 16x16 map: col = lane&15, row = (lane>>4)*4 + r.
  const int rbase = brow * BT + wr * 64 + (lane >> 4) * 4;
  const int cbase = bcol * BT + wc * 64 + (lane & 15);
  float lsum;
  if (brow == bcol)
    lsum = softplus_sum<true>(acc, rbase, cbase);
  else
    lsum = softplus_sum<false>(acc, rbase, cbase);

#pragma unroll
  for (int off = 32; off > 0; off >>= 1) lsum += __shfl_down(lsum, off);

  // Reuse the (dead) B buffer for cross-wave reduction (keeps LDS at 48 KB).
  float* wsum = (float*)(lds + 32768);
  __syncthreads();
  if (lane == 0) wsum[wave] = lsum;
  __syncthreads();
  if (tid == 0)
    partials[blockIdx.y * gridDim.x + blockIdx.x] =
        wsum[0] + wsum[1] + wsum[2] + wsum[3];
}

__global__ void reduce_kernel(const float* __restrict__ partials, int n,
                              float* __restrict__ out) {
  __shared__ float s[256];
  float v = 0.f;
  for (int i = threadIdx.x; i < n; i += 256) v += partials[i];
  s[threadIdx.x] = v;
  __syncthreads();
  for (int off = 128; off > 0; off >>= 1) {
    if ((int)threadIdx.x < off) s[threadIdx.x] += s[threadIdx.x + off];
    __syncthreads();
  }
  if (threadIdx.x == 0) out[0] = s[0] / (float)B_DIM;
}

extern "C" void kernel_launch(void* const* d_in, const int* in_sizes, int n_in,
                              void* d_out, int out_size, void* d_ws, size_t ws_size,
                              hipStream_t stream) {
  const float* emb1 = (const float*)d_in[0];
  const float* emb2 = (const float*)d_in[1];

  unsigned char* A8 = (unsigned char*)d_ws;                // 8 MB (bricked)
  unsigned char* B8 = A8 + (size_t)B_DIM * K_DIM;          // 8 MB (bricked)
  float* partials = (float*)(B8 + (size_t)B_DIM * K_DIM);  // 16 KB

  const float INV_T = 1.0f / 0.07f;
  const int nbA = (B_DIM * K_DIM / 16) / 256;  // 2048 blocks per operand
  cvt_fused<<<2 * nbA, 256, 0, stream>>>(emb1, emb2, A8, B8, nbA, INV_T);

  dim3 grid(B_DIM / BT, B_DIM / BT);  // 64 x 64
  siglip_gemm<<<grid, 256, 0, stream>>>(A8, B8, partials);

  const int nparts = (B_DIM / BT) * (B_DIM / BT);
  reduce_kernel<<<1, 256, 0, stream>>>(partials, nparts, (float*)d_out);
}